// Round 12
// baseline (62.627 us; speedup 1.0000x reference)
//
#include <hip/hip_runtime.h>
#include <cfloat>

#define NEG_INF_F (-1e30f)

constexpr int BB = 8, SS = 4096, HH = 1024;
constexpr int TOTAL = BB * SS;   // 32768 rows
constexpr int MAXLEN = 30;
constexpr int RPB = 64;          // stage-1 rows per block
constexpr int CPT = 8;           // candidates per thread (ceil(30/4))
constexpr int BLK_PER_B = SS / RPB;          // 64
constexpr int S1_GRID = BB * BLK_PER_B;      // 512

// ---------------- Kernel 1: QA-head GEMV + masking ----------------
// NOTE: plain __launch_bounds__(256) only — a min-waves hint caps VGPRs and
// serializes the 12 in-flight loads (R6/R8: 370 GB/s disaster).
__global__ __launch_bounds__(256) void qa_logits_kernel(
    const float* __restrict__ X,     // (B*S, H)
    const float* __restrict__ mask,  // (B*S)
    const float* __restrict__ W,     // (H, 2) row-major
    const float* __restrict__ bqa,   // (2)
    float* __restrict__ out) {       // [0,TOTAL): start, [TOTAL,2*TOTAL): end
  int row  = (int)((blockIdx.x * (size_t)blockDim.x + threadIdx.x) >> 6);
  int lane = threadIdx.x & 63;
  if (row >= TOTAL) return;
  const float* rp = X + (size_t)row * HH;
  float s0 = 0.f, s1 = 0.f;
#pragma unroll
  for (int k = 0; k < HH / 256; ++k) {
    int h = (k * 64 + lane) * 4;
    const float4 x   = *reinterpret_cast<const float4*>(rp + h);
    const float4 w01 = *reinterpret_cast<const float4*>(W + 2 * h);
    const float4 w23 = *reinterpret_cast<const float4*>(W + 2 * h + 4);
    s0 += x.x * w01.x + x.y * w01.z + x.z * w23.x + x.w * w23.z;
    s1 += x.x * w01.y + x.y * w01.w + x.z * w23.y + x.w * w23.w;
  }
#pragma unroll
  for (int off = 32; off > 0; off >>= 1) {
    s0 += __shfl_down(s0, off);
    s1 += __shfl_down(s1, off);
  }
  if (lane == 0) {
    float m = mask[row];
    float inv = 1.f - m;
    out[row]         = (s0 + bqa[0]) * m + inv * NEG_INF_F;
    out[TOTAL + row] = (s1 + bqa[1]) * m + inv * NEG_INF_F;
  }
}

// ---------- packed u64 key: (sortable-float << 32) | (~idx) ----------
__device__ __forceinline__ unsigned long long pack_key(float v, unsigned idx) {
  unsigned u = __float_as_uint(v);
  u = (u & 0x80000000u) ? ~u : (u | 0x80000000u);
  return ((unsigned long long)u << 32) | (unsigned long long)(0xFFFFFFFFu - idx);
}

__device__ __forceinline__ void k5_insert(unsigned long long k[5], unsigned long long nk) {
  if (nk <= k[4]) return;
  k[4] = nk;
  unsigned long long t;
  if (k[4] > k[3]) { t = k[3]; k[3] = k[4]; k[4] = t; }
  if (k[3] > k[2]) { t = k[2]; k[2] = k[3]; k[3] = t; }
  if (k[2] > k[1]) { t = k[1]; k[1] = k[2]; k[2] = t; }
  if (k[1] > k[0]) { t = k[0]; k[0] = k[1]; k[1] = t; }
}

__device__ __forceinline__ void wave_top5_u64(unsigned long long k[5],
                                              unsigned long long r[5]) {
#pragma unroll
  for (int q = 0; q < 5; ++q) {
    unsigned long long m = k[0];
    if (k[1] > m) m = k[1];
    if (k[2] > m) m = k[2];
    if (k[3] > m) m = k[3];
    if (k[4] > m) m = k[4];
#pragma unroll
    for (int off = 1; off < 64; off <<= 1) {
      unsigned long long o = __shfl_xor(m, off);
      if (o > m) m = o;
    }
    r[q] = m;
#pragma unroll
    for (int p = 0; p < 5; ++p)
      if (k[p] == m) k[p] = 0ull;  // keys unique; invalidate winner
  }
}

// ---------------- Stage 1: short-chain LDS-staged banded top-5 (R11) --------
__global__ __launch_bounds__(256) void topk_stage1(
    const float* __restrict__ logits,      // gemv output (start then end)
    unsigned long long* __restrict__ ws) { // (S1_GRID, 5) block top-5 keys
  const int b  = blockIdx.x / BLK_PER_B;
  const int rb = blockIdx.x % BLK_PER_B;
  const int i0 = rb * RPB;
  const int t  = (int)threadIdx.x;
  const int lane = t & 63;
  const int w = t >> 6;

  __shared__ float s_st[RPB];
  __shared__ float s_en[RPB + 32];  // 96 floats: window tail + NEG_INF pad
  __shared__ unsigned long long sk[4 * 5];

  const float* st = logits + (size_t)b * SS + i0;
  const float* en = logits + (size_t)(BB + b) * SS + i0;
  const int n_en = min(SS - i0, RPB + MAXLEN - 1);  // 93 (64 for last chunk)

  if (t < 16) {
    *reinterpret_cast<float4*>(&s_st[t * 4]) =
        *reinterpret_cast<const float4*>(st + t * 4);
  } else if (t < 40) {
    int r = t - 16;
    if (r * 4 + 4 <= n_en)
      *reinterpret_cast<float4*>(&s_en[r * 4]) =
          *reinterpret_cast<const float4*>(en + r * 4);
    else
#pragma unroll
      for (int c = 0; c < 4; ++c)
        s_en[r * 4 + c] = (r * 4 + c < n_en) ? en[r * 4 + c] : NEG_INF_F;
  }
  __syncthreads();

  unsigned long long k5[5] = {0, 0, 0, 0, 0};
  const int lr = t >> 2;       // local row 0..63
  const int sub = t & 3;       // candidate slice
  const int i = i0 + lr;

  if (i >= 4) {
    float sv = s_st[lr];
    int c0 = sub * CPT;
    float e[CPT];
#pragma unroll
    for (int c = 0; c < CPT; ++c)  // unguarded LDS reads (max idx 94 < 96)
      e[c] = (c0 + c < MAXLEN) ? s_en[lr + c0 + c] : NEG_INF_F;
    unsigned base = (unsigned)(i * SS + i + c0);
#pragma unroll
    for (int c = 0; c < CPT; ++c) k5_insert(k5, pack_key(sv + e[c], base + c));
  } else if (i >= 1 && sub == 0) {  // spans (1,1),(2,2),(3,3)
    k5_insert(k5, pack_key(s_st[lr] + s_en[lr], (unsigned)(i * SS + i)));
  }

  unsigned long long r5[5];
  wave_top5_u64(k5, r5);
  if (lane == 0) {
#pragma unroll
    for (int q = 0; q < 5; ++q) sk[w * 5 + q] = r5[q];
  }
  __syncthreads();

  if (w == 0) {  // merge 4 waves * 5 = 20 keys -> block top-5
    unsigned long long m5[5] = {0, 0, 0, 0, 0};
    if (lane < 20) m5[0] = sk[lane];
    unsigned long long f5[5];
    wave_top5_u64(m5, f5);
    if (lane == 0) {
#pragma unroll
      for (int q = 0; q < 5; ++q) ws[blockIdx.x * 5 + q] = f5[q];
    }
  }
}

// ---------------- Stage 2: per-batch merge of 64 blocks * 5 = 320 keys ------
__global__ __launch_bounds__(64) void topk_stage2(
    const unsigned long long* __restrict__ ws,
    float* __restrict__ out) {
  const int b = blockIdx.x;
  const int lane = (int)threadIdx.x;
  const unsigned long long* src = ws + (size_t)b * BLK_PER_B * 5;  // 320 keys

  unsigned long long k5[5];
#pragma unroll
  for (int q = 0; q < 5; ++q) k5[q] = src[q * 64 + lane];  // exactly 5/lane

  unsigned long long r5[5];
  wave_top5_u64(k5, r5);

  if (lane == 0) {
    float* ts = out + 2 * (size_t)TOTAL;  // top_start region
    float* te = ts + BB * 5;              // top_end region
#pragma unroll
    for (int q = 0; q < 5; ++q) {
      unsigned idx = 0xFFFFFFFFu - (unsigned)(r5[q] & 0xFFFFFFFFull);
      ts[b * 5 + q] = (float)(idx >> 12);       // idx / S  (S=4096)
      te[b * 5 + q] = (float)(idx & (SS - 1));  // idx % S
    }
  }
}

extern "C" void kernel_launch(void* const* d_in, const int* in_sizes, int n_in,
                              void* d_out, int out_size, void* d_ws, size_t ws_size,
                              hipStream_t stream) {
  const float* X    = (const float*)d_in[0];  // (B,S,H)
  const float* mask = (const float*)d_in[1];  // (B,S)
  const float* W    = (const float*)d_in[2];  // (H,2)
  const float* bqa  = (const float*)d_in[3];  // (2)
  float* out = (float*)d_out;
  unsigned long long* ws = (unsigned long long*)d_ws;  // S1_GRID*5 u64 = 20 KB

  qa_logits_kernel<<<TOTAL / 4, 256, 0, stream>>>(X, mask, W, bqa, out);

  // MEASUREMENT ROUND: stage1/stage2 are idempotent (same in -> same out), so
  // duplicating them is correctness-neutral. dur_us - 34.7 = 3*(s1 + s2)
  // marginal cost, separating dispatch exec+ramp from fixed overhead.
  topk_stage1<<<S1_GRID, 256, 0, stream>>>(out, ws);
  topk_stage1<<<S1_GRID, 256, 0, stream>>>(out, ws);
  topk_stage1<<<S1_GRID, 256, 0, stream>>>(out, ws);
  topk_stage1<<<S1_GRID, 256, 0, stream>>>(out, ws);
  topk_stage2<<<BB, 64, 0, stream>>>(ws, out);
  topk_stage2<<<BB, 64, 0, stream>>>(ws, out);
  topk_stage2<<<BB, 64, 0, stream>>>(ws, out);
  topk_stage2<<<BB, 64, 0, stream>>>(ws, out);
}

// Round 13
// 42.114 us; speedup vs baseline: 1.4871x; 1.4871x over previous
//
#include <hip/hip_runtime.h>
#include <cfloat>

#define NEG_INF_F (-1e30f)

constexpr int BB = 8, SS = 4096, HH = 1024;
constexpr int TOTAL = BB * SS;   // 32768 rows
constexpr int MAXLEN = 30;
constexpr int RPB = 64;          // topk rows per block
constexpr int CPT = 8;           // candidates per thread (ceil(30/4))
constexpr int BLK_PER_B = SS / RPB;          // 64
constexpr int TK_GRID = BB * BLK_PER_B;      // 512

// ---------------- Kernel 1: QA-head GEMV + masking (proven ~20.5 us) ---------
// NOTE: plain __launch_bounds__(256) only — a min-waves hint caps VGPRs and
// serializes the 12 in-flight loads (R6/R8: 370 GB/s disaster).
__global__ __launch_bounds__(256) void qa_logits_kernel(
    const float* __restrict__ X,     // (B*S, H)
    const float* __restrict__ mask,  // (B*S)
    const float* __restrict__ W,     // (H, 2) row-major
    const float* __restrict__ bqa,   // (2)
    float* __restrict__ out,         // [0,TOTAL): start, [TOTAL,2*TOTAL): end
    unsigned* __restrict__ cnt) {    // (BB) ticket counters for topk
  if (blockIdx.x == 0 && threadIdx.x < BB) cnt[threadIdx.x] = 0u;
  int row  = (int)((blockIdx.x * (size_t)blockDim.x + threadIdx.x) >> 6);
  int lane = threadIdx.x & 63;
  if (row >= TOTAL) return;
  const float* rp = X + (size_t)row * HH;
  float s0 = 0.f, s1 = 0.f;
#pragma unroll
  for (int k = 0; k < HH / 256; ++k) {
    int h = (k * 64 + lane) * 4;
    const float4 x   = *reinterpret_cast<const float4*>(rp + h);
    const float4 w01 = *reinterpret_cast<const float4*>(W + 2 * h);
    const float4 w23 = *reinterpret_cast<const float4*>(W + 2 * h + 4);
    s0 += x.x * w01.x + x.y * w01.z + x.z * w23.x + x.w * w23.z;
    s1 += x.x * w01.y + x.y * w01.w + x.z * w23.y + x.w * w23.w;
  }
#pragma unroll
  for (int off = 32; off > 0; off >>= 1) {
    s0 += __shfl_down(s0, off);
    s1 += __shfl_down(s1, off);
  }
  if (lane == 0) {
    float m = mask[row];
    float inv = 1.f - m;
    out[row]         = (s0 + bqa[0]) * m + inv * NEG_INF_F;
    out[TOTAL + row] = (s1 + bqa[1]) * m + inv * NEG_INF_F;
  }
}

// ---------- packed u64 key: (sortable-float << 32) | (~idx) ----------
// Higher key = higher value, then lower flat index (jax top_k tie-break).
// Validated end-to-end in rounds 8-12.
__device__ __forceinline__ unsigned long long pack_key(float v, unsigned idx) {
  unsigned u = __float_as_uint(v);
  u = (u & 0x80000000u) ? ~u : (u | 0x80000000u);
  return ((unsigned long long)u << 32) | (unsigned long long)(0xFFFFFFFFu - idx);
}

// Sorted-descending 5-key insert, early exit (keys unique, 0 = sentinel).
__device__ __forceinline__ void k5_insert(unsigned long long k[5], unsigned long long nk) {
  if (nk <= k[4]) return;
  k[4] = nk;
  unsigned long long t;
  if (k[4] > k[3]) { t = k[3]; k[3] = k[4]; k[4] = t; }
  if (k[3] > k[2]) { t = k[2]; k[2] = k[3]; k[3] = t; }
  if (k[2] > k[1]) { t = k[1]; k[1] = k[2]; k[2] = t; }
  if (k[1] > k[0]) { t = k[0]; k[0] = k[1]; k[1] = t; }
}

// Wave-wide top-5 via 5 argmax rounds on u64 keys; result same in all lanes.
__device__ __forceinline__ void wave_top5_u64(unsigned long long k[5],
                                              unsigned long long r[5]) {
#pragma unroll
  for (int q = 0; q < 5; ++q) {
    unsigned long long m = k[0];
    if (k[1] > m) m = k[1];
    if (k[2] > m) m = k[2];
    if (k[3] > m) m = k[3];
    if (k[4] > m) m = k[4];
#pragma unroll
    for (int off = 1; off < 64; off <<= 1) {
      unsigned long long o = __shfl_xor(m, off);
      if (o > m) m = o;
    }
    r[q] = m;
#pragma unroll
    for (int p = 0; p < 5; ++p)
      if (k[p] == m) k[p] = 0ull;  // keys unique; invalidate winner
  }
}

// ---------------- Kernel 2: single-dispatch banded top-5 --------------------
// R11's proven scan (512 blocks x 256 threads, 64 rows/block, 4 thr/row,
// LDS-staged window, short 8-insert chains) + R7/R10's proven agent-scope
// ticket tail: last block per batch merges 64x5=320 keys in-wave.
__global__ __launch_bounds__(256) void topk_kernel(
    const float* __restrict__ logits,      // gemv output (start then end)
    float* __restrict__ out,
    unsigned long long* __restrict__ ws,   // (TK_GRID, 5) block top-5 keys
    unsigned* __restrict__ cnt) {          // (BB), zeroed by gemv
  const int b  = blockIdx.x / BLK_PER_B;
  const int rb = blockIdx.x % BLK_PER_B;
  const int i0 = rb * RPB;
  const int t  = (int)threadIdx.x;
  const int lane = t & 63;
  const int w = t >> 6;

  __shared__ float s_st[RPB];
  __shared__ float s_en[RPB + 32];  // 96 floats: window tail + NEG_INF pad
  __shared__ unsigned long long sk[4 * 5];

  const float* st = logits + (size_t)b * SS + i0;
  const float* en = logits + (size_t)(BB + b) * SS + i0;
  const int n_en = min(SS - i0, RPB + MAXLEN - 1);  // 93 (64 for last chunk)

  if (t < 16) {
    *reinterpret_cast<float4*>(&s_st[t * 4]) =
        *reinterpret_cast<const float4*>(st + t * 4);
  } else if (t < 40) {
    int r = t - 16;
    if (r * 4 + 4 <= n_en)
      *reinterpret_cast<float4*>(&s_en[r * 4]) =
          *reinterpret_cast<const float4*>(en + r * 4);
    else
#pragma unroll
      for (int c = 0; c < 4; ++c)
        s_en[r * 4 + c] = (r * 4 + c < n_en) ? en[r * 4 + c] : NEG_INF_F;
  }
  __syncthreads();

  unsigned long long k5[5] = {0, 0, 0, 0, 0};
  const int lr = t >> 2;       // local row 0..63
  const int sub = t & 3;       // candidate slice
  const int i = i0 + lr;

  if (i >= 4) {
    float sv = s_st[lr];
    int c0 = sub * CPT;
    float e[CPT];
#pragma unroll
    for (int c = 0; c < CPT; ++c)  // unguarded LDS reads (max idx 94 < 96)
      e[c] = (c0 + c < MAXLEN) ? s_en[lr + c0 + c] : NEG_INF_F;
    unsigned base = (unsigned)(i * SS + i + c0);
#pragma unroll
    for (int c = 0; c < CPT; ++c) k5_insert(k5, pack_key(sv + e[c], base + c));
  } else if (i >= 1 && sub == 0) {  // spans (1,1),(2,2),(3,3)
    k5_insert(k5, pack_key(s_st[lr] + s_en[lr], (unsigned)(i * SS + i)));
  }

  unsigned long long r5[5];
  wave_top5_u64(k5, r5);
  if (lane == 0) {
#pragma unroll
    for (int q = 0; q < 5; ++q) sk[w * 5 + q] = r5[q];
  }
  __syncthreads();

  if (w == 0) {  // wave 0: merge 4 waves * 5 = 20 keys -> block top-5
    unsigned long long m5[5] = {0, 0, 0, 0, 0};
    if (lane < 20) m5[0] = sk[lane];
    unsigned long long f5[5];
    wave_top5_u64(m5, f5);

    // publish block result + ticket (mechanism proven R7/R10)
    unsigned old = 0;
    if (lane == 0) {
#pragma unroll
      for (int q = 0; q < 5; ++q)
        __hip_atomic_store(&ws[blockIdx.x * 5 + q], f5[q],
                           __ATOMIC_RELAXED, __HIP_MEMORY_SCOPE_AGENT);
      __threadfence();  // release: block result visible before ticket
      old = __hip_atomic_fetch_add(&cnt[b], 1u, __ATOMIC_RELAXED,
                                   __HIP_MEMORY_SCOPE_AGENT);
    }
    old = __shfl(old, 0);

    if (old == (unsigned)(BLK_PER_B - 1)) {  // last block of batch b
      __threadfence();                       // acquire
      const unsigned long long* src = ws + (size_t)b * BLK_PER_B * 5;  // 320
      unsigned long long g5[5];
#pragma unroll
      for (int q = 0; q < 5; ++q)            // exactly 5 keys per lane
        g5[q] = __hip_atomic_load(&src[lane * 5 + q], __ATOMIC_RELAXED,
                                  __HIP_MEMORY_SCOPE_AGENT);
      unsigned long long h5[5];
      wave_top5_u64(g5, h5);
      if (lane == 0) {
        float* ts = out + 2 * (size_t)TOTAL;  // top_start region
        float* te = ts + BB * 5;              // top_end region
#pragma unroll
        for (int q = 0; q < 5; ++q) {
          unsigned idx = 0xFFFFFFFFu - (unsigned)(h5[q] & 0xFFFFFFFFull);
          ts[b * 5 + q] = (float)(idx >> 12);       // idx / S  (S=4096)
          te[b * 5 + q] = (float)(idx & (SS - 1));  // idx % S
        }
      }
    }
  }
}

extern "C" void kernel_launch(void* const* d_in, const int* in_sizes, int n_in,
                              void* d_out, int out_size, void* d_ws, size_t ws_size,
                              hipStream_t stream) {
  const float* X    = (const float*)d_in[0];  // (B,S,H)
  const float* mask = (const float*)d_in[1];  // (B,S)
  const float* W    = (const float*)d_in[2];  // (H,2)
  const float* bqa  = (const float*)d_in[3];  // (2)
  float* out = (float*)d_out;

  unsigned long long* ws = (unsigned long long*)d_ws;  // TK_GRID*5 u64 = 20 KB
  unsigned* cnt = (unsigned*)((char*)d_ws + TK_GRID * 5 * sizeof(unsigned long long));

  qa_logits_kernel<<<TOTAL / 4, 256, 0, stream>>>(X, mask, W, bqa, out, cnt);
  topk_kernel<<<TK_GRID, 256, 0, stream>>>(out, out, ws, cnt);
}

// Round 14
// 34.322 us; speedup vs baseline: 1.8247x; 1.2270x over previous
//
#include <hip/hip_runtime.h>
#include <cfloat>

#define NEG_INF_F (-1e30f)

constexpr int BB = 8, SS = 4096, HH = 1024;
constexpr int TOTAL = BB * SS;   // 32768 rows
constexpr int MAXLEN = 30;
constexpr int RPW = 16;          // rows per wave (4 threads/row, 8 cand/thread)
constexpr int WPB = 4;           // waves per block
constexpr int RPB = RPW * WPB;   // 64 rows per block
constexpr int BLK_PER_B = SS / RPB;          // 64
constexpr int S1_GRID = BB * BLK_PER_B;      // 512 blocks = 2048 waves
constexpr int WAVES_PER_B = BLK_PER_B * WPB; // 256 waves per batch

// ---------------- Kernel 1: QA-head GEMV + masking (proven ~20.5 us) ---------
// NOTE: plain __launch_bounds__(256) only — a min-waves hint caps VGPRs and
// serializes the 12 in-flight loads (R6/R8: 370 GB/s disaster).
__global__ __launch_bounds__(256) void qa_logits_kernel(
    const float* __restrict__ X,     // (B*S, H)
    const float* __restrict__ mask,  // (B*S)
    const float* __restrict__ W,     // (H, 2) row-major
    const float* __restrict__ bqa,   // (2)
    float* __restrict__ out) {       // [0,TOTAL): start, [TOTAL,2*TOTAL): end
  int row  = (int)((blockIdx.x * (size_t)blockDim.x + threadIdx.x) >> 6);
  int lane = threadIdx.x & 63;
  if (row >= TOTAL) return;
  const float* rp = X + (size_t)row * HH;
  float s0 = 0.f, s1 = 0.f;
#pragma unroll
  for (int k = 0; k < HH / 256; ++k) {
    int h = (k * 64 + lane) * 4;
    const float4 x   = *reinterpret_cast<const float4*>(rp + h);
    const float4 w01 = *reinterpret_cast<const float4*>(W + 2 * h);
    const float4 w23 = *reinterpret_cast<const float4*>(W + 2 * h + 4);
    s0 += x.x * w01.x + x.y * w01.z + x.z * w23.x + x.w * w23.z;
    s1 += x.x * w01.y + x.y * w01.w + x.z * w23.y + x.w * w23.w;
  }
#pragma unroll
  for (int off = 32; off > 0; off >>= 1) {
    s0 += __shfl_down(s0, off);
    s1 += __shfl_down(s1, off);
  }
  if (lane == 0) {
    float m = mask[row];
    float inv = 1.f - m;
    out[row]         = (s0 + bqa[0]) * m + inv * NEG_INF_F;
    out[TOTAL + row] = (s1 + bqa[1]) * m + inv * NEG_INF_F;
  }
}

// ---------- packed u64 key: (sortable-float << 32) | (~idx) ----------
// Higher key = higher value, then lower flat index (jax top_k tie-break).
// Validated end-to-end in rounds 8-13.
__device__ __forceinline__ unsigned long long pack_key(float v, unsigned idx) {
  unsigned u = __float_as_uint(v);
  u = (u & 0x80000000u) ? ~u : (u | 0x80000000u);
  return ((unsigned long long)u << 32) | (unsigned long long)(0xFFFFFFFFu - idx);
}

// Sorted-descending 5-key insert, early exit (keys unique, 0 = sentinel).
__device__ __forceinline__ void k5_insert(unsigned long long k[5], unsigned long long nk) {
  if (nk <= k[4]) return;
  k[4] = nk;
  unsigned long long t;
  if (k[4] > k[3]) { t = k[3]; k[3] = k[4]; k[4] = t; }
  if (k[3] > k[2]) { t = k[2]; k[2] = k[3]; k[3] = t; }
  if (k[2] > k[1]) { t = k[1]; k[1] = k[2]; k[2] = t; }
  if (k[1] > k[0]) { t = k[0]; k[0] = k[1]; k[1] = t; }
}

// Wave-wide top-5 via 5 argmax rounds on u64 keys; result same in all lanes.
__device__ __forceinline__ void wave_top5_u64(unsigned long long k[5],
                                              unsigned long long r[5]) {
#pragma unroll
  for (int q = 0; q < 5; ++q) {
    unsigned long long m = k[0];
    if (k[1] > m) m = k[1];
    if (k[2] > m) m = k[2];
    if (k[3] > m) m = k[3];
    if (k[4] > m) m = k[4];
#pragma unroll
    for (int off = 1; off < 64; off <<= 1) {
      unsigned long long o = __shfl_xor(m, off);
      if (o > m) m = o;
    }
    r[q] = m;
#pragma unroll
    for (int p = 0; p < 5; ++p)
      if (k[p] == m) k[p] = 0ull;  // keys unique; invalidate winner
  }
}

// ---------------- Stage 1: barrier-free direct-load banded top-5 ------------
// 512 blocks x 256 threads = 2048 independent waves; wave = 16 rows x 4 subs.
// Logits are L2-resident (freshly written, 256 KB) -> direct global loads,
// all 8 issued in parallel, NO LDS, NO __syncthreads, ONE wave_top5 on the
// critical path. Each wave writes its own 5 keys.
__global__ __launch_bounds__(256) void topk_stage1(
    const float* __restrict__ logits,      // gemv output (start then end)
    unsigned long long* __restrict__ ws) { // (2048 waves, 5) keys
  const int t = (int)threadIdx.x;
  const int lane = t & 63;
  const int w = t >> 6;
  const int b  = blockIdx.x / BLK_PER_B;
  const int rb = blockIdx.x % BLK_PER_B;
  const int lr = lane >> 2;            // row within wave 0..15
  const int sub = lane & 3;            // candidate slice
  const int i = rb * RPB + w * RPW + lr;

  const float* st = logits + (size_t)b * SS;
  const float* en = logits + (size_t)(BB + b) * SS;

  unsigned long long k5[5] = {0, 0, 0, 0, 0};
  const float sv = st[i];              // 4 lanes share -> broadcast fetch

  if (i >= 4) {
    const int c0 = sub * 8;
    float e[8];
#pragma unroll
    for (int c = 0; c < 8; ++c) {
      int cc = c0 + c;
      int j = i + cc;
      // Unguarded load: max addr = logits[2*TOTAL-1 + 30] < out_size (65616).
      // OOB-of-batch values (next batch's logits / top-idx region) are
      // replaced by NEG_INF via the select below.
      float v = en[j];
      e[c] = (cc < MAXLEN && j < SS) ? v : NEG_INF_F;
    }
    unsigned base = (unsigned)(i * SS + i + c0);
#pragma unroll
    for (int c = 0; c < 8; ++c) k5_insert(k5, pack_key(sv + e[c], base + c));
  } else if (i >= 1 && sub == 0) {     // spans (1,1),(2,2),(3,3)
    k5_insert(k5, pack_key(sv + en[i], (unsigned)(i * SS + i)));
  }

  unsigned long long r5[5];
  wave_top5_u64(k5, r5);

  if (lane == 0) {
    const int wave_id = blockIdx.x * WPB + w;
#pragma unroll
    for (int q = 0; q < 5; ++q) ws[wave_id * 5 + q] = r5[q];
  }
}

// ---------------- Stage 2: per-batch merge of 256 waves * 5 = 1280 keys -----
__global__ __launch_bounds__(64) void topk_stage2(
    const unsigned long long* __restrict__ ws,
    float* __restrict__ out) {
  const int b = blockIdx.x;
  const int lane = (int)threadIdx.x;
  const unsigned long long* src = ws + (size_t)b * WAVES_PER_B * 5;  // 1280

  unsigned long long g[20];
#pragma unroll
  for (int q = 0; q < 20; ++q) g[q] = src[q * 64 + lane];  // coalesced, parallel

  unsigned long long k5[5] = {0, 0, 0, 0, 0};
#pragma unroll
  for (int q = 0; q < 20; ++q) k5_insert(k5, g[q]);

  unsigned long long r5[5];
  wave_top5_u64(k5, r5);

  if (lane == 0) {
    float* ts = out + 2 * (size_t)TOTAL;  // top_start region
    float* te = ts + BB * 5;              // top_end region
#pragma unroll
    for (int q = 0; q < 5; ++q) {
      unsigned idx = 0xFFFFFFFFu - (unsigned)(r5[q] & 0xFFFFFFFFull);
      ts[b * 5 + q] = (float)(idx >> 12);       // idx / S  (S=4096)
      te[b * 5 + q] = (float)(idx & (SS - 1));  // idx % S
    }
  }
}

extern "C" void kernel_launch(void* const* d_in, const int* in_sizes, int n_in,
                              void* d_out, int out_size, void* d_ws, size_t ws_size,
                              hipStream_t stream) {
  const float* X    = (const float*)d_in[0];  // (B,S,H)
  const float* mask = (const float*)d_in[1];  // (B,S)
  const float* W    = (const float*)d_in[2];  // (H,2)
  const float* bqa  = (const float*)d_in[3];  // (2)
  float* out = (float*)d_out;
  unsigned long long* ws = (unsigned long long*)d_ws;  // 2048*5 u64 = 80 KB

  qa_logits_kernel<<<TOTAL / 4, 256, 0, stream>>>(X, mask, W, bqa, out);
  topk_stage1<<<S1_GRID, 256, 0, stream>>>(out, ws);
  topk_stage2<<<BB, 64, 0, stream>>>(ws, out);
}